// Round 12
// baseline (372.422 us; speedup 1.0000x reference)
//
#include <hip/hip_runtime.h>
#include <hip/hip_bf16.h>

typedef __attribute__((ext_vector_type(8))) short bf16x8;
typedef __attribute__((ext_vector_type(4))) float f32x4;
typedef __attribute__((ext_vector_type(4))) unsigned int u32x4;
typedef __attribute__((ext_vector_type(4))) unsigned short u16x4;

// ---------------- bf16 helpers ----------------
__device__ __forceinline__ unsigned short f2bf(float f) {
  __hip_bfloat16 h = __float2bfloat16(f);
  return __builtin_bit_cast(unsigned short, h);
}

// ---------------- init: Wigner 3j coefficients + weight transpose ----------------
struct cplx { double re, im; };
__device__ __forceinline__ cplx cmul(cplx a, cplx b) {
  return {a.re * b.re - a.im * b.im, a.re * b.im + a.im * b.re};
}
__device__ __forceinline__ double fct_(int n) {
  const double f[8] = {1., 1., 2., 6., 24., 120., 720., 5040.};
  return f[n];
}
__device__ __forceinline__ int imax_(int a, int b) { return a > b ? a : b; }
__device__ __forceinline__ int imin_(int a, int b) { return a < b ? a : b; }

__device__ double su2_cg(int j1, int j2, int j3, int m1, int m2, int m3) {
  if (m3 != m1 + m2) return 0.0;
  int vmin = imax_(imax_(-j1 + j2 + m3, -j1 + m1), 0);
  int vmax = imin_(imin_(j2 + j3 + m1, j3 - j1 + j2), j3 + m3);
  double C = sqrt((2.0 * j3 + 1.0) * fct_(j3 + j1 - j2) * fct_(j3 - j1 + j2) * fct_(j1 + j2 - j3)
                  * fct_(j3 + m3) * fct_(j3 - m3)
                  / (fct_(j1 + j2 + j3 + 1) * fct_(j1 - m1) * fct_(j1 + m1) * fct_(j2 - m2) * fct_(j2 + m2)));
  double S = 0.0;
  for (int v = vmin; v <= vmax; ++v) {
    double sgn = ((v + j2 + m2) & 1) ? -1.0 : 1.0;
    S += sgn * fct_(j2 + j3 + m1 - v) * fct_(j1 - m1 + v)
         / (fct_(v) * fct_(j3 - j1 + j2 - v) * fct_(j3 + m3 - v) * fct_(v + j1 - j2 - m3));
  }
  return C * S;
}

__device__ cplx q_entry(int l, int r, int c) {
  const double s2 = 0.70710678118654752440;
  int m = r - l;
  cplx v = {0.0, 0.0};
  if (m < 0) {
    if (c == l - m) v = {s2, 0.0};
    else if (c == l + m) v = {0.0, -s2};
  } else if (m == 0) {
    if (c == l) v = {1.0, 0.0};
  } else {
    double sgn = (m & 1) ? -1.0 : 1.0;
    if (c == l + m) v = {sgn * s2, 0.0};
    else if (c == l - m) v = {0.0, sgn * s2};
  }
  cplx f;
  switch (l & 3) {
    case 0: f = {1.0, 0.0}; break;
    case 1: f = {0.0, -1.0}; break;
    case 2: f = {-1.0, 0.0}; break;
    default: f = {0.0, 1.0}; break;
  }
  return cmul(f, v);
}

// blocks 0..703: transpose weights fp32 [p][u][w] -> bf16 [p][w][u]
// blocks 704..714: Wigner 3j * path-normalization into cgw[p*125 + i*25 + j*5 + k]
// block 715: pack g-metadata GMAP[e] for the 115 (p,i,k) fold entries
__global__ void init_kernel(const float* __restrict__ w, unsigned short* __restrict__ Wt,
                            float* __restrict__ cgw, unsigned int* __restrict__ gmap) {
  const int blk = blockIdx.x;
  const int tid = threadIdx.x;
  if (blk < 704) {
    int g = blk * 256 + tid;                 // 704*256 == 180224 exactly
    int p = g >> 14, rem = g & 16383;
    int u = rem >> 7, wc = rem & 127;
    Wt[(p << 14) + (wc << 7) + u] = f2bf(w[g]);
    return;
  }
  if (blk == 715) {
    if (tid < 115) {
      const int PBt[12] = {0,1,4,9,18,21,36,45,70,85,90,115};
      const int D2t[11] = {1,3,5,1,3,3,5,1,3,5,5};
      const int D3t[11] = {1,3,5,3,1,5,3,5,3,1,5};
      const int O2t[11] = {0,1,4,0,1,1,4,0,1,4,4};
      int p = 0;
      while (tid >= PBt[p + 1]) ++p;
      int le = tid - PBt[p];
      int i = le / D3t[p], k = le % D3t[p];
      gmap[tid] = ((unsigned)(p * 125 + i * 25 + k) << 8) | (O2t[p] << 4) | D2t[p];
    }
    return;
  }
  const int p = blk - 704;
  const int L1t[11] = {0,0,0,1,1,1,1,2,2,2,2};
  const int L2t[11] = {0,1,2,0,1,1,2,0,1,2,2};
  const int L3t[11] = {0,1,2,1,0,2,1,2,1,0,2};
  const double FAN[11] = {384.,512.,512.,512.,384.,512.,512.,512.,512.,384.,512.};
  const int l1 = L1t[p], l2 = L2t[p], l3 = L3t[p];
  const int n1 = 2 * l1 + 1, n2 = 2 * l2 + 1, n3 = 2 * l3 + 1;
  if (tid >= n1 * n2 * n3) return;
  const int a = tid / (n2 * n3), b = (tid / n3) % n2, c = tid % n3;
  double sre = 0.0;
  for (int i = 0; i < n1; ++i)
    for (int k = 0; k < n2; ++k)
      for (int n = 0; n < n3; ++n) {
        double cg = su2_cg(l1, l2, l3, i - l1, k - l2, n - l3);
        if (cg == 0.0) continue;
        cplx q1 = q_entry(l1, i, a);
        cplx q2 = q_entry(l2, k, b);
        cplx q3 = q_entry(l3, n, c);
        q3.im = -q3.im;                      // conj(Q3)
        cplx pr = cmul(cmul(q1, q2), q3);
        sre += pr.re * cg;
      }
  cgw[p * 125 + a * 25 + b * 5 + c] = (float)(sre / sqrt(FAN[p]));
}

// ---------------- main kernel ----------------
// LDS x1 tile: PLANE-MAJOR bf16. 9 planes (l1=0: 1, l1=1: 3, l1=2: 5), each
// 16 rows x 128 u at pitch 132 shorts. Plane pi base = pi*2112 shorts.
// Total 19008 shorts = 38016 B. g_lds[e][row16] f32: 115 x 16 = 7360 B.
__device__ __forceinline__ void stage_all(const float* __restrict__ x1, int Mbase,
                                          unsigned short* __restrict__ s_a) {
  const int tid = threadIdx.x;
#pragma unroll 4
  for (int rep = 0; rep < 18; ++rep) {
    int it = tid + rep * 256;                // 4608 float4-loads total
    int row = it / 288, c4 = it % 288;
    int col = c4 << 2;                       // float4 never straddles groups
    const f32x4 v = __builtin_nontemporal_load(
        (const f32x4*)&x1[(size_t)(Mbase + row) * 1152 + col]);
    unsigned short* sr = s_a + row * 132;
    if (col < 128) {
      u16x4 h;
#pragma unroll
      for (int q = 0; q < 4; ++q) h[q] = f2bf(v[q]);
      *(u16x4*)&sr[col] = h;
    } else if (col < 512) {
      int cc = col - 128;
#pragma unroll
      for (int q = 0; q < 4; ++q) {
        int u = (cc + q) / 3, i = (cc + q) % 3;
        sr[(1 + i) * 2112 + u] = f2bf(v[q]);
      }
    } else {
      int cc = col - 512;
#pragma unroll
      for (int q = 0; q < 4; ++q) {
        int u = (cc + q) / 5, i = (cc + q) % 5;
        sr[(4 + i) * 2112 + u] = f2bf(v[q]);
      }
    }
  }
}

// y_p[b,i,w] = sum_u x1[b,u,i] * W_p[u,w]  (MFMA GEMM per component i), then
// fold acc[k] += g[b,i,k] * y_i. Planes in PAIRS, and each y SPLIT into
// even/odd-us halves: 8 independent 2-deep MFMA chains per pair (R11 had
// 4 chains 4-deep -> latency-bound at 26% issue). Pair loop stays unroll-1.
template<int PID, int L1, int L3, int PBASE>
__device__ __forceinline__ void do_path(const unsigned short* __restrict__ s_a,
                                        const float* __restrict__ g_lds,
                                        const unsigned short* __restrict__ Wt,
                                        int kg, int r16, int nbase,
                                        f32x4 (&acc)[2 * L3 + 1][2]) {
  constexpr int D1 = 2 * L1 + 1, D3 = 2 * L3 + 1;
  constexpr int GB = (L1 == 0) ? 0 : ((L1 == 1) ? 2112 : 8448);
  const unsigned short* __restrict__ wbase = Wt + (PID << 14);
  // all 8 weight frags once per path (32 VGPRs, loaded from L2 once)
  u32x4 bw[2][4];
#pragma unroll
  for (int nf = 0; nf < 2; ++nf)
#pragma unroll
    for (int us = 0; us < 4; ++us)
      bw[nf][us] = *(const u32x4*)&wbase[(nbase + nf * 16 + r16) * 128 + us * 32 + kg * 8];
  const unsigned short* __restrict__ ap0 = s_a + GB + r16 * 132 + kg * 8;
  // ---- plane pairs ----
#pragma unroll 1
  for (int ii = 0; ii + 1 < D1; ii += 2) {
    const unsigned short* apA = ap0 + ii * 2112;
    const unsigned short* apB = apA + 2112;
    // split-y: [plane][nf][even/odd us] -> 8 independent 2-deep chains
    f32x4 y0[2][2] = {{f32x4{0.f,0.f,0.f,0.f}, f32x4{0.f,0.f,0.f,0.f}},
                      {f32x4{0.f,0.f,0.f,0.f}, f32x4{0.f,0.f,0.f,0.f}}};
    f32x4 y1[2][2] = {{f32x4{0.f,0.f,0.f,0.f}, f32x4{0.f,0.f,0.f,0.f}},
                      {f32x4{0.f,0.f,0.f,0.f}, f32x4{0.f,0.f,0.f,0.f}}};
#pragma unroll
    for (int us = 0; us < 4; ++us) {
      const u32x4 a0 = *(const u32x4*)(apA + us * 32);
      const u32x4 a1 = *(const u32x4*)(apB + us * 32);
      const int h = us & 1;
#pragma unroll
      for (int nf = 0; nf < 2; ++nf) {
        y0[nf][h] = __builtin_amdgcn_mfma_f32_16x16x32_bf16(
            __builtin_bit_cast(bf16x8, a0), __builtin_bit_cast(bf16x8, bw[nf][us]),
            y0[nf][h], 0, 0, 0);
        y1[nf][h] = __builtin_amdgcn_mfma_f32_16x16x32_bf16(
            __builtin_bit_cast(bf16x8, a1), __builtin_bit_cast(bf16x8, bw[nf][us]),
            y1[nf][h], 0, 0, 0);
      }
    }
#pragma unroll
    for (int k = 0; k < D3; ++k) {
      const f32x4 gA = *(const f32x4*)&g_lds[((PBASE + ii * D3 + k) << 4) + (kg << 2)];
      const f32x4 gB = *(const f32x4*)&g_lds[((PBASE + (ii + 1) * D3 + k) << 4) + (kg << 2)];
#pragma unroll
      for (int nf = 0; nf < 2; ++nf) {
        acc[k][nf] += gA * (y0[nf][0] + y0[nf][1]);
        acc[k][nf] += gB * (y1[nf][0] + y1[nf][1]);
      }
    }
  }
  // ---- odd tail plane ----
  if (D1 & 1) {
    constexpr int it = D1 - 1;
    const unsigned short* ap = ap0 + it * 2112;
    f32x4 y[2][2] = {{f32x4{0.f,0.f,0.f,0.f}, f32x4{0.f,0.f,0.f,0.f}},
                     {f32x4{0.f,0.f,0.f,0.f}, f32x4{0.f,0.f,0.f,0.f}}};
#pragma unroll
    for (int us = 0; us < 4; ++us) {
      const u32x4 af = *(const u32x4*)(ap + us * 32);
      const int h = us & 1;
#pragma unroll
      for (int nf = 0; nf < 2; ++nf)
        y[nf][h] = __builtin_amdgcn_mfma_f32_16x16x32_bf16(
            __builtin_bit_cast(bf16x8, af), __builtin_bit_cast(bf16x8, bw[nf][us]),
            y[nf][h], 0, 0, 0);
    }
#pragma unroll
    for (int k = 0; k < D3; ++k) {
      const f32x4 g4 = *(const f32x4*)&g_lds[((PBASE + it * D3 + k) << 4) + (kg << 2)];
#pragma unroll
      for (int nf = 0; nf < 2; ++nf) acc[k][nf] += g4 * (y[nf][0] + y[nf][1]);
    }
  }
}

__global__ void __launch_bounds__(256, 2) fctp_main(
    const float* __restrict__ x1, const float* __restrict__ x2,
    const float* __restrict__ cgw, const unsigned int* __restrict__ gmap,
    const unsigned short* __restrict__ Wt, float* __restrict__ out) {
  __shared__ __align__(16) unsigned short s_a[19008];  // 38016 B plane-major x1
  __shared__ __align__(16) float g_lds[1840];          // 7360 B g[e][row]
  const int tid = threadIdx.x;
  const int Mbase = blockIdx.x << 4;

  stage_all(x1, Mbase, s_a);

  // cooperative g: g[e][row] = sum_j x2[Mbase+row][o2+j] * cgw[co + j*5]
#pragma unroll 1
  for (int t = tid; t < 1840; t += 256) {
    int row = t & 15, e = t >> 4;
    unsigned m = gmap[e];
    int d2 = m & 15, o2 = (m >> 4) & 15, co = m >> 8;
    const float* xp = x2 + (size_t)(Mbase + row) * 9 + o2;
    const float* cp = cgw + co;
    float s = 0.f;
    for (int j = 0; j < d2; ++j) s += xp[j] * cp[j * 5];
    g_lds[(e << 4) + row] = s;
  }

  const int lane = tid & 63, ni = tid >> 6;
  const int r16 = lane & 15, kg = lane >> 4;
  const int nbase = ni << 5;          // this wave's 32-wide w window

  __syncthreads();                    // x1 planes + g ready

  const int bout = Mbase + (kg << 2);

  // ---- i3 = 0 (cols [0,128), d3=1): paths 0,4,9 ----
  {
    f32x4 acc[1][2] = {};
    do_path<0, 0, 0, 0>(s_a, g_lds, Wt, kg, r16, nbase, acc);
    do_path<4, 1, 0, 18>(s_a, g_lds, Wt, kg, r16, nbase, acc);
    do_path<9, 2, 0, 85>(s_a, g_lds, Wt, kg, r16, nbase, acc);
#pragma unroll
    for (int nf = 0; nf < 2; ++nf) {
      const int w = nbase + nf * 16 + r16;
#pragma unroll
      for (int r = 0; r < 4; ++r)
        __builtin_nontemporal_store(acc[0][nf][r],
                                    &out[(size_t)(bout + r) * 1152 + w]);
    }
  }
  // ---- i3 = 1 (cols 128 + w*3 + k, d3=3): paths 1,3,6,8 ----
  {
    f32x4 acc[3][2] = {};
    do_path<1, 0, 1, 1>(s_a, g_lds, Wt, kg, r16, nbase, acc);
    do_path<3, 1, 1, 9>(s_a, g_lds, Wt, kg, r16, nbase, acc);
    do_path<6, 1, 1, 36>(s_a, g_lds, Wt, kg, r16, nbase, acc);
    do_path<8, 2, 1, 70>(s_a, g_lds, Wt, kg, r16, nbase, acc);
#pragma unroll
    for (int nf = 0; nf < 2; ++nf) {
      const int w = nbase + nf * 16 + r16;
#pragma unroll
      for (int r = 0; r < 4; ++r) {
        float* o = out + (size_t)(bout + r) * 1152 + 128 + w * 3;
#pragma unroll
        for (int k = 0; k < 3; ++k) o[k] = acc[k][nf][r];
      }
    }
  }
  // ---- i3 = 2 (cols 512 + w*5 + k, d3=5): paths 2,5,7,10 ----
  {
    f32x4 acc[5][2] = {};
    do_path<2, 0, 2, 4>(s_a, g_lds, Wt, kg, r16, nbase, acc);
    do_path<5, 1, 2, 21>(s_a, g_lds, Wt, kg, r16, nbase, acc);
    do_path<7, 2, 2, 45>(s_a, g_lds, Wt, kg, r16, nbase, acc);
    do_path<10, 2, 2, 90>(s_a, g_lds, Wt, kg, r16, nbase, acc);
#pragma unroll
    for (int nf = 0; nf < 2; ++nf) {
      const int w = nbase + nf * 16 + r16;
#pragma unroll
      for (int r = 0; r < 4; ++r) {
        float* o = out + (size_t)(bout + r) * 1152 + 512 + w * 5;
#pragma unroll
        for (int k = 0; k < 5; ++k) o[k] = acc[k][nf][r];
      }
    }
  }
}

extern "C" void kernel_launch(void* const* d_in, const int* in_sizes, int n_in,
                              void* d_out, int out_size, void* d_ws, size_t ws_size,
                              hipStream_t stream) {
  (void)in_sizes; (void)n_in; (void)out_size; (void)ws_size;
  const float* x1 = (const float*)d_in[0];
  const float* x2 = (const float*)d_in[1];
  const float* w  = (const float*)d_in[2];
  float* out = (float*)d_out;
  float* cgw = (float*)d_ws;                                     // 1375 floats
  unsigned int* gmap = (unsigned int*)((char*)d_ws + 5504);      // 115 u32
  unsigned short* Wt = (unsigned short*)((char*)d_ws + 8192);    // 11*128*128 bf16
  init_kernel<<<dim3(716), dim3(256), 0, stream>>>(w, Wt, cgw, gmap);
  fctp_main<<<dim3(4096), dim3(256), 0, stream>>>(x1, x2, cgw, gmap, Wt, out);
}

// Round 13
// 330.804 us; speedup vs baseline: 1.1258x; 1.1258x over previous
//
#include <hip/hip_runtime.h>
#include <hip/hip_bf16.h>

typedef __attribute__((ext_vector_type(8))) short bf16x8;
typedef __attribute__((ext_vector_type(4))) float f32x4;
typedef __attribute__((ext_vector_type(4))) unsigned int u32x4;
typedef __attribute__((ext_vector_type(2))) unsigned int u32x2;
typedef __attribute__((ext_vector_type(4))) unsigned short u16x4;

// ---------------- bf16 helpers ----------------
__device__ __forceinline__ unsigned short f2bf(float f) {
  __hip_bfloat16 h = __float2bfloat16(f);
  return __builtin_bit_cast(unsigned short, h);
}
__device__ __forceinline__ float bfw(unsigned int word, int hi) {
  union { unsigned int i; float f; } v;
  v.i = hi ? (word & 0xffff0000u) : (word << 16);
  return v.f;
}

// ---------------- init: Wigner 3j coefficients + weight transpose ----------------
struct cplx { double re, im; };
__device__ __forceinline__ cplx cmul(cplx a, cplx b) {
  return {a.re * b.re - a.im * b.im, a.re * b.im + a.im * b.re};
}
__device__ __forceinline__ double fct_(int n) {
  const double f[8] = {1., 1., 2., 6., 24., 120., 720., 5040.};
  return f[n];
}
__device__ __forceinline__ int imax_(int a, int b) { return a > b ? a : b; }
__device__ __forceinline__ int imin_(int a, int b) { return a < b ? a : b; }

__device__ double su2_cg(int j1, int j2, int j3, int m1, int m2, int m3) {
  if (m3 != m1 + m2) return 0.0;
  int vmin = imax_(imax_(-j1 + j2 + m3, -j1 + m1), 0);
  int vmax = imin_(imin_(j2 + j3 + m1, j3 - j1 + j2), j3 + m3);
  double C = sqrt((2.0 * j3 + 1.0) * fct_(j3 + j1 - j2) * fct_(j3 - j1 + j2) * fct_(j1 + j2 - j3)
                  * fct_(j3 + m3) * fct_(j3 - m3)
                  / (fct_(j1 + j2 + j3 + 1) * fct_(j1 - m1) * fct_(j1 + m1) * fct_(j2 - m2) * fct_(j2 + m2)));
  double S = 0.0;
  for (int v = vmin; v <= vmax; ++v) {
    double sgn = ((v + j2 + m2) & 1) ? -1.0 : 1.0;
    S += sgn * fct_(j2 + j3 + m1 - v) * fct_(j1 - m1 + v)
         / (fct_(v) * fct_(j3 - j1 + j2 - v) * fct_(j3 + m3 - v) * fct_(v + j1 - j2 - m3));
  }
  return C * S;
}

__device__ cplx q_entry(int l, int r, int c) {
  const double s2 = 0.70710678118654752440;
  int m = r - l;
  cplx v = {0.0, 0.0};
  if (m < 0) {
    if (c == l - m) v = {s2, 0.0};
    else if (c == l + m) v = {0.0, -s2};
  } else if (m == 0) {
    if (c == l) v = {1.0, 0.0};
  } else {
    double sgn = (m & 1) ? -1.0 : 1.0;
    if (c == l + m) v = {sgn * s2, 0.0};
    else if (c == l - m) v = {0.0, sgn * s2};
  }
  cplx f;
  switch (l & 3) {
    case 0: f = {1.0, 0.0}; break;
    case 1: f = {0.0, -1.0}; break;
    case 2: f = {-1.0, 0.0}; break;
    default: f = {0.0, 1.0}; break;
  }
  return cmul(f, v);
}

// blocks 0..703: transpose weights fp32 [p][u][w] -> bf16 [p][w][u]
// blocks 704..714: path p = blk-704: Wigner3j*norm -> cgw, then (race-free,
//                  via LDS + barrier) zero-padded per-e rows gfold[e][5]
// block 715: gmap[e] = o2 (x2 segment offset) for the 115 fold entries
__global__ void init_kernel(const float* __restrict__ w, unsigned short* __restrict__ Wt,
                            float* __restrict__ cgw, float* __restrict__ gfold,
                            unsigned int* __restrict__ gmap) {
  const int blk = blockIdx.x;
  const int tid = threadIdx.x;
  if (blk < 704) {
    int g = blk * 256 + tid;                 // 704*256 == 180224 exactly
    int p = g >> 14, rem = g & 16383;
    int u = rem >> 7, wc = rem & 127;
    Wt[(p << 14) + (wc << 7) + u] = f2bf(w[g]);
    return;
  }
  if (blk == 715) {
    if (tid < 115) {
      const int PBt[12] = {0,1,4,9,18,21,36,45,70,85,90,115};
      const int O2t[11] = {0,1,4,0,1,1,4,0,1,4,4};
      int p = 0;
      while (tid >= PBt[p + 1]) ++p;
      gmap[tid] = O2t[p];
    }
    return;
  }
  // path blocks
  __shared__ float s_cg[125];
  const int p = blk - 704;
  const int L1t[11] = {0,0,0,1,1,1,1,2,2,2,2};
  const int L2t[11] = {0,1,2,0,1,1,2,0,1,2,2};
  const int L3t[11] = {0,1,2,1,0,2,1,2,1,0,2};
  const int PBt[11] = {0,1,4,9,18,21,36,45,70,85,90};
  const double FAN[11] = {384.,512.,512.,512.,384.,512.,512.,512.,512.,384.,512.};
  const int l1 = L1t[p], l2 = L2t[p], l3 = L3t[p];
  const int n1 = 2 * l1 + 1, n2 = 2 * l2 + 1, n3 = 2 * l3 + 1;
  if (tid < n1 * n2 * n3) {
    const int a = tid / (n2 * n3), b = (tid / n3) % n2, c = tid % n3;
    double sre = 0.0;
    for (int i = 0; i < n1; ++i)
      for (int k = 0; k < n2; ++k)
        for (int n = 0; n < n3; ++n) {
          double cg = su2_cg(l1, l2, l3, i - l1, k - l2, n - l3);
          if (cg == 0.0) continue;
          cplx q1 = q_entry(l1, i, a);
          cplx q2 = q_entry(l2, k, b);
          cplx q3 = q_entry(l3, n, c);
          q3.im = -q3.im;                    // conj(Q3)
          cplx pr = cmul(cmul(q1, q2), q3);
          sre += pr.re * cg;
        }
    float val = (float)(sre / sqrt(FAN[p]));
    s_cg[a * 25 + b * 5 + c] = val;
    cgw[p * 125 + a * 25 + b * 5 + c] = val;
  }
  __syncthreads();
  if (tid < n1 * n3) {
    int i = tid / n3, k = tid % n3;
    for (int j = 0; j < 5; ++j)
      gfold[(PBt[p] + tid) * 5 + j] = (j < n2) ? s_cg[i * 25 + j * 5 + k] : 0.f;
  }
}

// ---------------- main kernel ----------------
// LDS x1 tile: PLANE-MAJOR bf16 with XOR chunk swizzle. 9 planes x 16 rows x
// 128 u, pitch 128 shorts; within a row, 8-short chunk c stored at c^row.
// Write side (reg-staged) and read side use the same XOR -> uniform 2
// lanes/bank on ds_read_b128 (same as old pitch-132, zero padding).
// Plane pi base = pi*2048 shorts. Total 18432 shorts = 36864 B.
// g: bf16 [e][row16], 1840 shorts = 3680 B. LDS total 40544 -> 4 blocks/CU.
__device__ __forceinline__ void stage_all(const float* __restrict__ x1, int Mbase,
                                          unsigned short* __restrict__ s_a) {
  const int tid = threadIdx.x;
#pragma unroll 4
  for (int rep = 0; rep < 18; ++rep) {
    int it = tid + rep * 256;                // 4608 float4-loads total
    int row = it / 288, c4 = it % 288;
    int col = c4 << 2;                       // float4 never straddles groups
    const f32x4 v = __builtin_nontemporal_load(
        (const f32x4*)&x1[(size_t)(Mbase + row) * 1152 + col]);
    unsigned short* sr = s_a + row * 128;
    if (col < 128) {
      u16x4 h;
#pragma unroll
      for (int q = 0; q < 4; ++q) h[q] = f2bf(v[q]);
      // col%8 in {0,4}: stays inside one 8-short chunk
      *(u16x4*)&sr[(((col >> 3) ^ row) << 3) + (col & 7)] = h;
    } else if (col < 512) {
      int cc = col - 128;
#pragma unroll
      for (int q = 0; q < 4; ++q) {
        int u = (cc + q) / 3, i = (cc + q) % 3;
        s_a[(1 + i) * 2048 + row * 128 + (((u >> 3) ^ row) << 3) + (u & 7)] = f2bf(v[q]);
      }
    } else {
      int cc = col - 512;
#pragma unroll
      for (int q = 0; q < 4; ++q) {
        int u = (cc + q) / 5, i = (cc + q) % 5;
        s_a[(4 + i) * 2048 + row * 128 + (((u >> 3) ^ row) << 3) + (u & 7)] = f2bf(v[q]);
      }
    }
  }
}

// y_p[b,i,w] = sum_u x1[b,u,i] * W_p[u,w]  (MFMA GEMM per component i), then
// fold acc[k] += g[b,i,k] * y_i. Planes in pairs, split-y (8 indep chains).
template<int PID, int L1, int L3, int PBASE>
__device__ __forceinline__ void do_path(const unsigned short* __restrict__ s_a,
                                        const unsigned short* __restrict__ s_g,
                                        const unsigned short* __restrict__ Wt,
                                        int kg, int r16, int nbase,
                                        f32x4 (&acc)[2 * L3 + 1][2]) {
  constexpr int D1 = 2 * L1 + 1, D3 = 2 * L3 + 1;
  constexpr int GB = (L1 == 0) ? 0 : ((L1 == 1) ? 2048 : 8192);
  const unsigned short* __restrict__ wbase = Wt + (PID << 14);
  // all 8 weight frags once per path (32 VGPRs, loaded from L2 once)
  u32x4 bw[2][4];
#pragma unroll
  for (int nf = 0; nf < 2; ++nf)
#pragma unroll
    for (int us = 0; us < 4; ++us)
      bw[nf][us] = *(const u32x4*)&wbase[(nbase + nf * 16 + r16) * 128 + us * 32 + kg * 8];
  const unsigned short* __restrict__ ap0 = s_a + GB + r16 * 128;
  // unpack a 4xbf16 g row-quad into f32x4
  auto gread = [&](int e) -> f32x4 {
    const u32x2 gd = *(const u32x2*)&s_g[(e << 4) + (kg << 2)];
    f32x4 r;
    r[0] = bfw(gd.x, 0); r[1] = bfw(gd.x, 1);
    r[2] = bfw(gd.y, 0); r[3] = bfw(gd.y, 1);
    return r;
  };
  // ---- plane pairs ----
#pragma unroll 1
  for (int ii = 0; ii + 1 < D1; ii += 2) {
    const unsigned short* apA = ap0 + ii * 2048;
    const unsigned short* apB = apA + 2048;
    f32x4 y0[2][2] = {{f32x4{0.f,0.f,0.f,0.f}, f32x4{0.f,0.f,0.f,0.f}},
                      {f32x4{0.f,0.f,0.f,0.f}, f32x4{0.f,0.f,0.f,0.f}}};
    f32x4 y1[2][2] = {{f32x4{0.f,0.f,0.f,0.f}, f32x4{0.f,0.f,0.f,0.f}},
                      {f32x4{0.f,0.f,0.f,0.f}, f32x4{0.f,0.f,0.f,0.f}}};
#pragma unroll
    for (int us = 0; us < 4; ++us) {
      const int soff = (((us * 4 + kg) ^ r16) << 3);
      const u32x4 a0 = *(const u32x4*)(apA + soff);
      const u32x4 a1 = *(const u32x4*)(apB + soff);
      const int h = us & 1;
#pragma unroll
      for (int nf = 0; nf < 2; ++nf) {
        y0[nf][h] = __builtin_amdgcn_mfma_f32_16x16x32_bf16(
            __builtin_bit_cast(bf16x8, a0), __builtin_bit_cast(bf16x8, bw[nf][us]),
            y0[nf][h], 0, 0, 0);
        y1[nf][h] = __builtin_amdgcn_mfma_f32_16x16x32_bf16(
            __builtin_bit_cast(bf16x8, a1), __builtin_bit_cast(bf16x8, bw[nf][us]),
            y1[nf][h], 0, 0, 0);
      }
    }
#pragma unroll
    for (int k = 0; k < D3; ++k) {
      const f32x4 gA = gread(PBASE + ii * D3 + k);
      const f32x4 gB = gread(PBASE + (ii + 1) * D3 + k);
#pragma unroll
      for (int nf = 0; nf < 2; ++nf) {
        acc[k][nf] += gA * (y0[nf][0] + y0[nf][1]);
        acc[k][nf] += gB * (y1[nf][0] + y1[nf][1]);
      }
    }
  }
  // ---- odd tail plane ----
  if (D1 & 1) {
    constexpr int it = D1 - 1;
    const unsigned short* ap = ap0 + it * 2048;
    f32x4 y[2][2] = {{f32x4{0.f,0.f,0.f,0.f}, f32x4{0.f,0.f,0.f,0.f}},
                     {f32x4{0.f,0.f,0.f,0.f}, f32x4{0.f,0.f,0.f,0.f}}};
#pragma unroll
    for (int us = 0; us < 4; ++us) {
      const int soff = (((us * 4 + kg) ^ r16) << 3);
      const u32x4 af = *(const u32x4*)(ap + soff);
      const int h = us & 1;
#pragma unroll
      for (int nf = 0; nf < 2; ++nf)
        y[nf][h] = __builtin_amdgcn_mfma_f32_16x16x32_bf16(
            __builtin_bit_cast(bf16x8, af), __builtin_bit_cast(bf16x8, bw[nf][us]),
            y[nf][h], 0, 0, 0);
    }
#pragma unroll
    for (int k = 0; k < D3; ++k) {
      const f32x4 g4 = gread(PBASE + it * D3 + k);
#pragma unroll
      for (int nf = 0; nf < 2; ++nf) acc[k][nf] += g4 * (y[nf][0] + y[nf][1]);
    }
  }
}

__global__ void __launch_bounds__(256, 2) fctp_main(
    const float* __restrict__ x1, const float* __restrict__ x2,
    const float* __restrict__ gfold, const unsigned int* __restrict__ gmap,
    const unsigned short* __restrict__ Wt, float* __restrict__ out) {
  __shared__ __align__(16) unsigned short s_a[18432];  // 36864 B swizzled planes
  __shared__ __align__(16) unsigned short s_g[1840];   // 3680 B bf16 g[e][row]
  const int tid = threadIdx.x;
  const int Mbase = blockIdx.x << 4;

  stage_all(x1, Mbase, s_a);

  // g-phase: row = tid&15 is iteration-invariant -> load the 9 x2 floats once;
  // e-iterations fully unrolled so gfold/gmap L2 loads issue in parallel
  // (R12's unroll-1 loop paid ~8 serial latencies per block).
  {
    const int row = tid & 15, e0 = tid >> 4;
    const float* __restrict__ xr = x2 + (size_t)(Mbase + row) * 9;
    float x2r[9];
#pragma unroll
    for (int j = 0; j < 9; ++j) x2r[j] = xr[j];
#pragma unroll
    for (int it = 0; it < 8; ++it) {
      const int e = e0 + it * 16;
      if (e < 115) {
        const int o2 = (int)gmap[e];
        const float* __restrict__ gf = gfold + e * 5;
        float s = 0.f;
#pragma unroll
        for (int j = 0; j < 5; ++j) s += gf[j] * x2r[o2 + j];
        s_g[(e << 4) + row] = f2bf(s);
      }
    }
  }

  const int lane = tid & 63, ni = tid >> 6;
  const int r16 = lane & 15, kg = lane >> 4;
  const int nbase = ni << 5;          // this wave's 32-wide w window

  __syncthreads();                    // x1 planes + g ready

  const int bout = Mbase + (kg << 2);

  // ---- i3 = 0 (cols [0,128), d3=1): paths 0,4,9 ----
  {
    f32x4 acc[1][2] = {};
    do_path<0, 0, 0, 0>(s_a, s_g, Wt, kg, r16, nbase, acc);
    do_path<4, 1, 0, 18>(s_a, s_g, Wt, kg, r16, nbase, acc);
    do_path<9, 2, 0, 85>(s_a, s_g, Wt, kg, r16, nbase, acc);
#pragma unroll
    for (int nf = 0; nf < 2; ++nf) {
      const int w = nbase + nf * 16 + r16;
#pragma unroll
      for (int r = 0; r < 4; ++r)
        __builtin_nontemporal_store(acc[0][nf][r],
                                    &out[(size_t)(bout + r) * 1152 + w]);
    }
  }
  // ---- i3 = 1 (cols 128 + w*3 + k, d3=3): paths 1,3,6,8 ----
  {
    f32x4 acc[3][2] = {};
    do_path<1, 0, 1, 1>(s_a, s_g, Wt, kg, r16, nbase, acc);
    do_path<3, 1, 1, 9>(s_a, s_g, Wt, kg, r16, nbase, acc);
    do_path<6, 1, 1, 36>(s_a, s_g, Wt, kg, r16, nbase, acc);
    do_path<8, 2, 1, 70>(s_a, s_g, Wt, kg, r16, nbase, acc);
#pragma unroll
    for (int nf = 0; nf < 2; ++nf) {
      const int w = nbase + nf * 16 + r16;
#pragma unroll
      for (int r = 0; r < 4; ++r) {
        float* o = out + (size_t)(bout + r) * 1152 + 128 + w * 3;
#pragma unroll
        for (int k = 0; k < 3; ++k) o[k] = acc[k][nf][r];
      }
    }
  }
  // ---- i3 = 2 (cols 512 + w*5 + k, d3=5): paths 2,5,7,10 ----
  {
    f32x4 acc[5][2] = {};
    do_path<2, 0, 2, 4>(s_a, s_g, Wt, kg, r16, nbase, acc);
    do_path<5, 1, 2, 21>(s_a, s_g, Wt, kg, r16, nbase, acc);
    do_path<7, 2, 2, 45>(s_a, s_g, Wt, kg, r16, nbase, acc);
    do_path<10, 2, 2, 90>(s_a, s_g, Wt, kg, r16, nbase, acc);
#pragma unroll
    for (int nf = 0; nf < 2; ++nf) {
      const int w = nbase + nf * 16 + r16;
#pragma unroll
      for (int r = 0; r < 4; ++r) {
        float* o = out + (size_t)(bout + r) * 1152 + 512 + w * 5;
#pragma unroll
        for (int k = 0; k < 5; ++k) o[k] = acc[k][nf][r];
      }
    }
  }
}

extern "C" void kernel_launch(void* const* d_in, const int* in_sizes, int n_in,
                              void* d_out, int out_size, void* d_ws, size_t ws_size,
                              hipStream_t stream) {
  (void)in_sizes; (void)n_in; (void)out_size; (void)ws_size;
  const float* x1 = (const float*)d_in[0];
  const float* x2 = (const float*)d_in[1];
  const float* w  = (const float*)d_in[2];
  float* out = (float*)d_out;
  float* cgw = (float*)d_ws;                                     // 1375 f32 @ 0
  unsigned int* gmap = (unsigned int*)((char*)d_ws + 5504);      // 115 u32
  float* gfold = (float*)((char*)d_ws + 6144);                   // 115*5 f32
  unsigned short* Wt = (unsigned short*)((char*)d_ws + 16384);   // 11*128*128 bf16
  init_kernel<<<dim3(716), dim3(256), 0, stream>>>(w, Wt, cgw, gfold, gmap);
  fctp_main<<<dim3(4096), dim3(256), 0, stream>>>(x1, x2, gfold, gmap, Wt, out);
}